// Round 4
// baseline (454.594 us; speedup 1.0000x reference)
//
#include <hip/hip_runtime.h>
#include <hip/hip_bf16.h>

// Problem constants (match reference)
#define BB 32
#define SS 2048
#define HH 1024
#define CC 5
#define TEMP_INV (1.0f/0.07f)

// ---------------------------------------------------------------------------
// K1: pooling weights — softmax over S of sum(logits[:,:,1:5])
// grid: 64 blocks = (b, which), block: 256. LDS-staged coalesced loads.
// Also zeroes the loss completion counter for this iteration (workspace is
// re-poisoned by the harness between iterations).
__global__ __launch_bounds__(256) void pool_weights(const float* __restrict__ alog,
                             const float* __restrict__ olog,
                             float* __restrict__ w_a,
                             float* __restrict__ w_o,
                             int* __restrict__ counter) {
    if (blockIdx.x == 0 && threadIdx.x == 0) *counter = 0;
    int b = blockIdx.x >> 1;
    int which = blockIdx.x & 1;
    const float* lg = which ? olog : alog;
    float* wout = which ? w_o : w_a;
    __shared__ float raw[SS * CC];   // 40 KB
    __shared__ float sl[SS];         // 8 KB
    __shared__ float red[256];
    int t = threadIdx.x;
    const float4* src = (const float4*)(lg + (size_t)b * SS * CC);
    float4* dst = (float4*)raw;
    #pragma unroll 4
    for (int i = t; i < SS * CC / 4; i += 256) dst[i] = src[i];
    __syncthreads();
    for (int s = t; s < SS; s += 256) {
        int base = s * 5;
        sl[s] = raw[base + 1] + raw[base + 2] + raw[base + 3] + raw[base + 4];
    }
    __syncthreads();
    float m = -1e30f;
    for (int s = t; s < SS; s += 256) m = fmaxf(m, sl[s]);
    red[t] = m;
    __syncthreads();
    for (int o = 128; o > 0; o >>= 1) {
        if (t < o) red[t] = fmaxf(red[t], red[t + o]);
        __syncthreads();
    }
    m = red[0];
    __syncthreads();
    float sum = 0.f;
    for (int s = t; s < SS; s += 256) {
        float e = expf(sl[s] - m);
        sl[s] = e;
        sum += e;
    }
    red[t] = sum;
    __syncthreads();
    for (int o = 128; o > 0; o >>= 1) {
        if (t < o) red[t] += red[t + o];
        __syncthreads();
    }
    float inv = 1.0f / red[0];
    for (int s = t; s < SS; s += 256) wout[(size_t)b * SS + s] = sl[s] * inv;
}

// ---------------------------------------------------------------------------
// K2: pooling main pass — part[chunk][b][h] = sum over 64 s of span*w
// grid: 1024 = b(32) x chunk(32), block: 256 threads, 4 h each (float4)
// 268 MB streaming kernel; 16 float4 loads in flight per thread.
__global__ __launch_bounds__(256) void pool_partial(const float* __restrict__ span,
                             const float* __restrict__ w_a,
                             const float* __restrict__ w_o,
                             float* __restrict__ part_a,
                             float* __restrict__ part_o) {
    int b = blockIdx.x >> 5;
    int chunk = blockIdx.x & 31;
    int t = threadIdx.x;
    __shared__ float wa[64], wo[64];
    int s0 = chunk * 64;
    if (t < 64) {
        wa[t] = w_a[(size_t)b * SS + s0 + t];
        wo[t] = w_o[(size_t)b * SS + s0 + t];
    }
    __syncthreads();
    const float4* sp = (const float4*)span + ((size_t)b * SS + s0) * (HH / 4) + t;
    float4 aa = {0.f, 0.f, 0.f, 0.f};
    float4 oo = {0.f, 0.f, 0.f, 0.f};
    #pragma unroll 16
    for (int ss = 0; ss < 64; ++ss) {
        float4 v = sp[(size_t)ss * (HH / 4)];
        float fa = wa[ss], fo = wo[ss];
        aa.x += v.x * fa; aa.y += v.y * fa; aa.z += v.z * fa; aa.w += v.w * fa;
        oo.x += v.x * fo; oo.y += v.y * fo; oo.z += v.z * fo; oo.w += v.w * fo;
    }
    size_t idx = ((size_t)chunk * BB + b) * HH + (size_t)t * 4;
    *(float4*)(part_a + idx) = aa;
    *(float4*)(part_o + idx) = oo;
}

// K2r: reduce 32 partials -> a_emb/o_emb [32][1024]
__global__ __launch_bounds__(256) void pool_reduce(const float* __restrict__ part_a,
                            const float* __restrict__ part_o,
                            float* __restrict__ a_emb,
                            float* __restrict__ o_emb) {
    int gid = blockIdx.x * 256 + threadIdx.x;
    int which = gid >> 15;
    int r = gid & 32767;
    const float* p = which ? part_o : part_a;
    float s = 0.f;
    #pragma unroll
    for (int c = 0; c < 32; ++c) s += p[(size_t)c * 32768 + r];
    (which ? o_emb : a_emb)[r] = s;
}

// ---------------------------------------------------------------------------
// K3: all three layer-1 GEMMs. ROUND-4: float4 W loads (each thread owns 4
// consecutive j), 16 FMA per 16B load (was 4 FMA per 4B load), k-tile 64.
// grid: 384 = a[0,64) (4jt x 16kb), o[64,128), s[128,384) (8jt x 32kb).
// block 256 = 32 j-quads (128 j) x 8 b-groups (4 batch rows each).
__global__ __launch_bounds__(256) void gemm1_all(const float* __restrict__ a_emb, const float* __restrict__ o_emb,
                          const float* __restrict__ Wa1, const float* __restrict__ Wo1,
                          const float* __restrict__ Ws1,
                          float* __restrict__ p1_a, float* __restrict__ p1_o,
                          float* __restrict__ p1_s) {
    int bid = blockIdx.x;
    const float* xp; const float* W; float* part; int N, kb, jt;
    if (bid < 64) {
        jt = bid & 3; kb = bid >> 2; N = 512; W = Wa1; part = p1_a;
        xp = a_emb + kb * 64;
    } else if (bid < 128) {
        int r = bid - 64;
        jt = r & 3; kb = r >> 2; N = 512; W = Wo1; part = p1_o;
        xp = o_emb + kb * 64;
    } else {
        int r = bid - 128;
        jt = r & 7; kb = r >> 3; N = 1024; W = Ws1; part = p1_s;
        int kk0 = kb * 64;   // 64-tiles never straddle the 1024 boundary
        xp = (kk0 < 1024) ? (a_emb + kk0) : (o_emb + (kk0 - 1024));
    }
    int k0 = kb * 64;
    __shared__ float xs[32][64];   // 8 KB
    int t = threadIdx.x;
    #pragma unroll
    for (int i = 0; i < 2; ++i) {
        int f = t + i * 256;        // float4 index into [32][16]
        int b = f >> 4;
        int kk = (f & 15) << 2;
        *(float4*)(&xs[b][kk]) = *(const float4*)(xp + (size_t)b * HH + kk);
    }
    __syncthreads();
    int jq = t & 31, bg = t >> 5;   // 32 quads x 8 groups
    int j = jt * 128 + jq * 4;
    float4 a0 = {0,0,0,0}, a1 = {0,0,0,0}, a2 = {0,0,0,0}, a3 = {0,0,0,0};
    const float* Wp = W + (size_t)k0 * N + j;
    int b0 = bg * 4;
    #pragma unroll 8
    for (int k = 0; k < 64; ++k) {
        float4 w4 = *(const float4*)(Wp + (size_t)k * N);
        float x0 = xs[b0 + 0][k], x1 = xs[b0 + 1][k];
        float x2 = xs[b0 + 2][k], x3 = xs[b0 + 3][k];
        a0.x += w4.x * x0; a0.y += w4.y * x0; a0.z += w4.z * x0; a0.w += w4.w * x0;
        a1.x += w4.x * x1; a1.y += w4.y * x1; a1.z += w4.z * x1; a1.w += w4.w * x1;
        a2.x += w4.x * x2; a2.y += w4.y * x2; a2.z += w4.z * x2; a2.w += w4.w * x2;
        a3.x += w4.x * x3; a3.y += w4.y * x3; a3.z += w4.z * x3; a3.w += w4.w * x3;
    }
    float* pp = part + (size_t)kb * 32 * N + j;
    *(float4*)(pp + (size_t)(b0 + 0) * N) = a0;
    *(float4*)(pp + (size_t)(b0 + 1) * N) = a1;
    *(float4*)(pp + (size_t)(b0 + 2) * N) = a2;
    *(float4*)(pp + (size_t)(b0 + 3) * N) = a3;
}

// ---------------------------------------------------------------------------
// K4: layer 2, fused k-split reduce + bias + relu of layer1, float4 W loads,
// float4 LDS tree-reduce, wave-level L2-norm.
// grid: 96: [0,32)=a, [32,64)=o, [64,96)=s. block: 512.
__global__ __launch_bounds__(512) void layer2_all(const float* __restrict__ p1_a, const float* __restrict__ ba1,
                           const float* __restrict__ Wa2, const float* __restrict__ ba2,
                           const float* __restrict__ p1_o, const float* __restrict__ bo1,
                           const float* __restrict__ Wo2, const float* __restrict__ bo2,
                           const float* __restrict__ p1_s, const float* __restrict__ bs1,
                           const float* __restrict__ Ws2, const float* __restrict__ bs2,
                           float* __restrict__ a_proj, float* __restrict__ o_proj,
                           float* __restrict__ s_proj) {
    __shared__ float x[1024];
    __shared__ float4 red4[512];   // 8 KB
    int bid = blockIdx.x;
    int t = threadIdx.x;
    if (bid < 64) {
        int which = bid >> 5;
        int b = bid & 31;
        const float* part = which ? p1_o : p1_a;
        const float* b1 = which ? bo1 : ba1;
        const float* W2 = which ? Wo2 : Wa2;
        const float* b2 = which ? bo2 : ba2;
        float* out = (which ? o_proj : a_proj) + (size_t)b * 128;
        {   // reduce 16 k-split partials + bias + relu (t = j)
            float s = b1[t];
            #pragma unroll
            for (int kb = 0; kb < 16; ++kb) s += part[(size_t)kb * 16384 + (size_t)b * 512 + t];
            x[t] = fmaxf(s, 0.f);
        }
        __syncthreads();
        int jq = t & 31, kh = t >> 5;     // 32 j-quads (128 j), 16-way k split
        const float* Wc = W2 + (size_t)kh * 32 * 128 + jq * 4;
        float4 acc = {0,0,0,0};
        #pragma unroll 8
        for (int kk = 0; kk < 32; ++kk) {
            float4 w4 = *(const float4*)(Wc + (size_t)kk * 128);
            float xv = x[kh * 32 + kk];
            acc.x += w4.x * xv; acc.y += w4.y * xv; acc.z += w4.z * xv; acc.w += w4.w * xv;
        }
        red4[t] = acc;
        __syncthreads();
        for (int o = 8; o > 0; o >>= 1) {
            if (kh < o) {
                float4 u = red4[kh * 32 + jq], v = red4[(kh + o) * 32 + jq];
                u.x += v.x; u.y += v.y; u.z += v.z; u.w += v.w;
                red4[kh * 32 + jq] = u;
            }
            __syncthreads();
        }
        if (t < 32) {
            float4 tot = red4[t];
            float4 bq = *(const float4*)(b2 + t * 4);
            tot.x += bq.x; tot.y += bq.y; tot.z += bq.z; tot.w += bq.w;
            float ss = tot.x * tot.x + tot.y * tot.y + tot.z * tot.z + tot.w * tot.w;
            #pragma unroll
            for (int m = 16; m > 0; m >>= 1) ss += __shfl_xor(ss, m, 32);
            float inv = 1.0f / fmaxf(sqrtf(ss), 1e-12f);
            tot.x *= inv; tot.y *= inv; tot.z *= inv; tot.w *= inv;
            *(float4*)(out + t * 4) = tot;
        }
    } else {
        int b = bid - 64;
        #pragma unroll
        for (int i = 0; i < 2; ++i) {
            int j = t + i * 512;
            float s = bs1[j];
            #pragma unroll
            for (int kb = 0; kb < 32; ++kb) s += p1_s[(size_t)kb * 32768 + (size_t)b * 1024 + j];
            x[j] = fmaxf(s, 0.f);
        }
        __syncthreads();
        int jq = t & 63, kh = t >> 6;     // 64 j-quads (256 j), 8-way k split
        const float* Wc = Ws2 + (size_t)kh * 128 * 256 + jq * 4;
        float4 acc = {0,0,0,0};
        #pragma unroll 8
        for (int kk = 0; kk < 128; ++kk) {
            float4 w4 = *(const float4*)(Wc + (size_t)kk * 256);
            float xv = x[kh * 128 + kk];
            acc.x += w4.x * xv; acc.y += w4.y * xv; acc.z += w4.z * xv; acc.w += w4.w * xv;
        }
        red4[t] = acc;
        __syncthreads();
        for (int o = 4; o > 0; o >>= 1) {
            if (kh < o) {
                float4 u = red4[kh * 64 + jq], v = red4[(kh + o) * 64 + jq];
                u.x += v.x; u.y += v.y; u.z += v.z; u.w += v.w;
                red4[kh * 64 + jq] = u;
            }
            __syncthreads();
        }
        if (t < 64) {
            float4 tot = red4[t];
            float4 bq = *(const float4*)(bs2 + t * 4);
            tot.x += bq.x; tot.y += bq.y; tot.z += bq.z; tot.w += bq.w;
            float ss = tot.x * tot.x + tot.y * tot.y + tot.z * tot.z + tot.w * tot.w;
            #pragma unroll
            for (int m = 32; m > 0; m >>= 1) ss += __shfl_xor(ss, m, 64);
            float inv = 1.0f / fmaxf(sqrtf(ss), 1e-12f);
            tot.x *= inv; tot.y *= inv; tot.z *= inv; tot.w *= inv;
            *(float4*)(s_proj + (size_t)b * 256 + t * 4) = tot;
        }
    }
}

// ---------------------------------------------------------------------------
// K5: loss rows + last-block final combine (saves one launch). 32 blocks, one
// per sim row i; 8 threads per dot with shfl-group reduction; float4 LDS reads
// with interleaved granules. Last block to finish (device-scope atomic counter,
// release fence before add, agent-scope loads after) does the deterministic
// fixed-order combine.
__global__ __launch_bounds__(256) void loss_rows(const float* __restrict__ a_proj,
                            const float* __restrict__ o_proj,
                            const float* __restrict__ s_proj,
                            const int* __restrict__ labels,
                            float* __restrict__ rowbuf,
                            int* __restrict__ counter,
                            float* __restrict__ out) {
    int i = blockIdx.x;
    __shared__ __align__(16) float spn[BB][260];   // 256 + 4 pad
    __shared__ __align__(16) float opn[BB][132];   // 128 + 4 pad
    __shared__ __align__(16) float api[128];
    __shared__ float invn[BB];
    __shared__ float jv[BB][5];
    __shared__ int lab[BB];
    int t = threadIdx.x;
    for (int q = t; q < 2048; q += 256) {
        int r = q >> 6, c = (q & 63) << 2;
        *(float4*)&spn[r][c] = *(const float4*)(s_proj + r * 256 + c);
    }
    for (int q = t; q < 1024; q += 256) {
        int r = q >> 5, c = (q & 31) << 2;
        *(float4*)&opn[r][c] = *(const float4*)(o_proj + r * 128 + c);
    }
    if (t < 32) *(float4*)&api[t * 4] = *(const float4*)(a_proj + (size_t)i * 128 + t * 4);
    if (t < BB) lab[t] = labels[t];
    __syncthreads();

    int r = t >> 3, l = t & 7;   // 32 groups of 8 lanes
    {
        float ssq = 0.f;
        #pragma unroll
        for (int q = 0; q < 8; ++q) {
            int c = (q * 8 + l) * 4;
            float4 v = *(float4*)&spn[r][c];
            ssq += v.x * v.x + v.y * v.y + v.z * v.z + v.w * v.w;
        }
        ssq += __shfl_xor(ssq, 1, 8);
        ssq += __shfl_xor(ssq, 2, 8);
        ssq += __shfl_xor(ssq, 4, 8);
        if (l == 0) invn[r] = 1.0f / fmaxf(sqrtf(ssq), 1e-12f);
    }
    __syncthreads();
    {
        float s = invn[r];
        #pragma unroll
        for (int q = 0; q < 8; ++q) {
            int c = (q * 8 + l) * 4;
            float4 v = *(float4*)&spn[r][c];
            v.x *= s; v.y *= s; v.z *= s; v.w *= s;
            *(float4*)&spn[r][c] = v;
        }
    }
    __syncthreads();

    int j = r;
    float dot = 0.f;
    #pragma unroll
    for (int q = 0; q < 4; ++q) {
        int c = (q * 8 + l) * 4;
        float4 av = *(float4*)&api[c];
        float4 ov = *(float4*)&opn[j][c];
        dot += av.x * ov.x + av.y * ov.y + av.z * ov.z + av.w * ov.w;
    }
    float dn = 0.f;
    #pragma unroll
    for (int q = 0; q < 8; ++q) {
        int c = (q * 8 + l) * 4;
        float4 si = *(float4*)&spn[i][c];
        float4 sj = *(float4*)&spn[j][c];
        dn += si.x * sj.x + si.y * sj.y + si.z * sj.z + si.w * sj.w;
    }
    dot += __shfl_xor(dot, 1, 8); dot += __shfl_xor(dot, 2, 8); dot += __shfl_xor(dot, 4, 8);
    dn  += __shfl_xor(dn, 1, 8);  dn  += __shfl_xor(dn, 2, 8);  dn  += __shfl_xor(dn, 4, 8);
    if (l == 0) {
        float e = expf(dot * TEMP_INV);
        float maskv = (i == j) ? 1.0f : ((lab[i] == lab[j]) ? 0.5f : 0.0f);
        float en = expf(dn * TEMP_INV);
        float mnt = (lab[i] == lab[j]) ? ((i == j) ? 0.f : 1.f) : 0.f;
        jv[j][0] = e * maskv;
        jv[j][1] = e;
        jv[j][2] = en * mnt;
        jv[j][3] = en * (1.f - mnt);
        jv[j][4] = mnt;
    }
    __syncthreads();
    if (t < 32) {
        float num = jv[t][0], den = jv[t][1], pos = jv[t][2], neg = jv[t][3], pc = jv[t][4];
        for (int m = 16; m > 0; m >>= 1) {
            num += __shfl_xor(num, m, 32);
            den += __shfl_xor(den, m, 32);
            pos += __shfl_xor(pos, m, 32);
            neg += __shfl_xor(neg, m, 32);
            pc  += __shfl_xor(pc, m, 32);
        }
        if (t == 0) {
            rowbuf[i] = -logf(num / den + 1e-8f);
            bool has = pc > 0.f;
            rowbuf[32 + i] = has ? (-logf(pos / (pos + neg) + 1e-8f) / fmaxf(pc, 1.0f)) : 0.f;
            rowbuf[64 + i] = has ? 1.f : 0.f;
        }
    }
    __syncthreads();
    if (t == 0) {
        __threadfence();   // release rowbuf writes, device scope
        int old = __hip_atomic_fetch_add(counter, 1, __ATOMIC_ACQ_REL, __HIP_MEMORY_SCOPE_AGENT);
        if (old == 31) {   // last block: combine in fixed order
            float inf = 0.f, nt = 0.f;
            int h = 0;
            #pragma unroll
            for (int q = 0; q < 32; ++q) {
                inf += __hip_atomic_load(&rowbuf[q], __ATOMIC_RELAXED, __HIP_MEMORY_SCOPE_AGENT);
                nt  += __hip_atomic_load(&rowbuf[32 + q], __ATOMIC_RELAXED, __HIP_MEMORY_SCOPE_AGENT);
                h   += (__hip_atomic_load(&rowbuf[64 + q], __ATOMIC_RELAXED, __HIP_MEMORY_SCOPE_AGENT) > 0.5f) ? 1 : 0;
            }
            inf /= (float)BB;
            nt /= (float)(h > 0 ? h : 1);
            out[0] = 1.0f * inf + 0.5f * nt;
        }
    }
}

// ---------------------------------------------------------------------------
extern "C" void kernel_launch(void* const* d_in, const int* in_sizes, int n_in,
                              void* d_out, int out_size, void* d_ws, size_t ws_size,
                              hipStream_t stream) {
    const float* span  = (const float*)d_in[0];
    const float* alog  = (const float*)d_in[1];
    const float* olog  = (const float*)d_in[2];
    const int*   labs  = (const int*)d_in[3];
    const float* Wa1   = (const float*)d_in[4];
    const float* ba1   = (const float*)d_in[5];
    const float* Wa2   = (const float*)d_in[6];
    const float* ba2   = (const float*)d_in[7];
    const float* Wo1   = (const float*)d_in[8];
    const float* bo1   = (const float*)d_in[9];
    const float* Wo2   = (const float*)d_in[10];
    const float* bo2   = (const float*)d_in[11];
    const float* Ws1   = (const float*)d_in[12];
    const float* bs1   = (const float*)d_in[13];
    const float* Ws2   = (const float*)d_in[14];
    const float* bs2   = (const float*)d_in[15];

    float* ws = (float*)d_ws;
    float* w_a    = ws;                  // 65536
    float* w_o    = ws + 65536;          // 65536
    float* part_a = ws + 131072;         // 32*32768 = 1048576
    float* part_o = ws + 1179648;        // 1048576
    float* a_emb  = ws + 2228224;        // 32768
    float* o_emb  = ws + 2260992;        // 32768
    float* p1_a   = ws + 2293760;        // 16*32*512 = 262144
    float* p1_o   = ws + 2555904;        // 262144
    float* p1_s   = ws + 2818048;        // 32*32*1024 = 1048576
    float* a_proj = ws + 3866624;        // 4096
    float* o_proj = ws + 3870720;        // 4096
    float* s_proj = ws + 3874816;        // 8192
    float* rowbuf = ws + 3883008;        // 96
    int*   counter = (int*)(ws + 3883104);

    hipLaunchKernelGGL(pool_weights, dim3(64), dim3(256), 0, stream,
                       alog, olog, w_a, w_o, counter);
    hipLaunchKernelGGL(pool_partial, dim3(1024), dim3(256), 0, stream,
                       span, w_a, w_o, part_a, part_o);
    hipLaunchKernelGGL(pool_reduce, dim3(256), dim3(256), 0, stream,
                       part_a, part_o, a_emb, o_emb);
    hipLaunchKernelGGL(gemm1_all, dim3(384), dim3(256), 0, stream,
                       a_emb, o_emb, Wa1, Wo1, Ws1, p1_a, p1_o, p1_s);
    hipLaunchKernelGGL(layer2_all, dim3(96), dim3(512), 0, stream,
                       p1_a, ba1, Wa2, ba2, p1_o, bo1, Wo2, bo2,
                       p1_s, bs1, Ws2, bs2, a_proj, o_proj, s_proj);
    hipLaunchKernelGGL(loss_rows, dim3(32), dim3(256), 0, stream,
                       a_proj, o_proj, s_proj, labs, rowbuf, counter, (float*)d_out);
}